// Round 11
// baseline (177.098 us; speedup 1.0000x reference)
//
#include <hip/hip_runtime.h>
#include <hip/hip_bf16.h>
#include <math.h>
#include <stdint.h>

// Problem constants (reference: BATCH=8, T=2048, N=512)
#define BATCH 8
#define T_LEN 2048
#define NDIM 512
#define M_ROWS (BATCH * T_LEN)   // 16384
#define CHUNK 32                 // scan chunk length
#define NCHUNK (T_LEN / CHUNK)   // 64

// X column layout (group-paired so one GEMM col-tile holds re+im of the
// same channels): col g*128 + j  (j<64)  = re of channel n = g*64+j
//                 col g*128 + 64 + j     = im of channel n = g*64+j

typedef __attribute__((ext_vector_type(8))) short bf16x8;
typedef __attribute__((ext_vector_type(4))) float floatx4;

// counted vmcnt wait (T4): wave waits until only n of its VMEM ops remain
// in flight; the following s_barrier makes completion collective.
#define VMWAIT(n) asm volatile("s_waitcnt vmcnt(" #n ")" ::: "memory")

__device__ __forceinline__ unsigned short f2bf(float f) {
    union { float f; unsigned u; } v; v.f = f;
    unsigned r = v.u + 0x7fff + ((v.u >> 16) & 1);   // RTNE
    return (unsigned short)(r >> 16);
}
__device__ __forceinline__ float bf2f(unsigned short h) {
    union { unsigned u; float f; } v; v.u = ((unsigned)h) << 16;
    return v.f;
}

// async global->LDS, 16 bytes per lane; LDS dest = wave-uniform base + lane*16.
__device__ __forceinline__ void gld_lds16(const unsigned short* g, unsigned short* l) {
    __builtin_amdgcn_global_load_lds(
        (const __attribute__((address_space(1))) unsigned int*)(uintptr_t)g,
        (__attribute__((address_space(3))) unsigned int*)(uintptr_t)l,
        16, 0, 0);
}

// ---------------- prep (merged): u->bf16  +  transpose/convert B,C ----------
__global__ __launch_bounds__(256) void k_prep(
    const float* __restrict__ u,
    const float* __restrict__ Bre, const float* __restrict__ Bim,
    const float* __restrict__ Cre, const float* __restrict__ Cim,
    const float* __restrict__ gamma,
    unsigned short* __restrict__ ubf,
    unsigned short* __restrict__ BT, unsigned short* __restrict__ CT)
{
    __shared__ unsigned short tile[32][33];
    const int blk = blockIdx.x;
    if (blk < 4096) {
        size_t i = ((size_t)blk * 256 + threadIdx.x) * 8;
        float4 a = *(const float4*)&u[i];
        float4 b = *(const float4*)&u[i + 4];
        ushort4 p0, p1;
        p0.x = f2bf(a.x); p0.y = f2bf(a.y); p0.z = f2bf(a.z); p0.w = f2bf(a.w);
        p1.x = f2bf(b.x); p1.y = f2bf(b.y); p1.z = f2bf(b.z); p1.w = f2bf(b.w);
        *(ushort4*)&ubf[i] = p0;
        *(ushort4*)&ubf[i + 4] = p1;
        return;
    }
    const int p = blk - 4096;
    const int z = p >> 8;                    // 0..3 (Bre,Bim,Cre,Cim)
    const int rem = p & 255;
    const int n0 = (rem & 15) * 32, k0 = (rem >> 4) * 32;
    const float* __restrict__ src = (z == 0) ? Bre : (z == 1) ? Bim : (z == 2) ? Cre : Cim;
    const int tx = threadIdx.x & 31, ty = threadIdx.x >> 5;   // ty 0..7

#pragma unroll
    for (int j = 0; j < 4; ++j) {
        int k = k0 + ty + j * 8;
        float s = (z < 2) ? gamma[k] : (z == 3 ? -1.f : 1.f);
        tile[ty + j * 8][tx] = f2bf(s * src[(size_t)k * NDIM + n0 + tx]);
    }
    __syncthreads();
#pragma unroll
    for (int j = 0; j < 4; ++j) {
        int n = n0 + ty + j * 8;
        unsigned short v = tile[tx][ty + j * 8];
        if (z == 0) {
            int row = ((n >> 6) << 7) + (n & 63);            // re-col of channel n
            BT[(size_t)row * 512 + k0 + tx] = v;
        } else if (z == 1) {
            int row = ((n >> 6) << 7) + 64 + (n & 63);       // im-col of channel n
            BT[(size_t)row * 512 + k0 + tx] = v;
        } else if (z == 2) {
            int k = k0 + tx;
            int col = ((k >> 6) << 7) + (k & 63);            // X re-col of channel k
            CT[(size_t)n * 1024 + col] = v;
        } else {
            int k = k0 + tx;
            int col = ((k >> 6) << 7) + 64 + (k & 63);       // X im-col of channel k
            CT[(size_t)n * 1024 + col] = v;
        }
    }
}

// ---------------- GEMM-in: X[16384][1024] = ubf[16384][512] @ BT^T ----------
// 256x256 tile, BK=64, 8 waves (2M x 4N), 2 LDS buffers, 4-phase-per-K-tile
// interleave (T3) with counted vmcnt (T4) + setprio (T5) + T2 swizzle.
// Fused scan pass A from the LDS-resident 256x256 output tile.  (unchanged)
__global__ __launch_bounds__(512) void k_gemm_in(
    const unsigned short* __restrict__ A,    // [16384][512] bf16
    const unsigned short* __restrict__ BT,   // [1024][512] bf16, X-col-major
    const float* __restrict__ nu, const float* __restrict__ theta,
    unsigned short* __restrict__ X,          // [16384][1024] bf16 out (pre-scan)
    float* __restrict__ carry)               // [b][c][n] float2 interleaved
{
    __shared__ unsigned short smem[65536];

    const int tid = threadIdx.x;
    const int w = tid >> 6, l = tid & 63;
    const int bm = blockIdx.x * 256;
    const int bn = blockIdx.y * 256;         // 256 X-cols = 128 channels
    const int wm = (w & 1) * 128, wn = (w >> 1) * 64;
    const int lm = l & 15, lq = l >> 4;
    const int sr = tid >> 3;                         // 0..63
    const int scw = ((tid & 7) ^ (sr & 7)) * 8;      // swizzled global col (shorts)
    const int scl = (tid & 7) * 8;                   // linear LDS col (shorts)
    const int rsw = (lm & 7) << 3;                   // read-side XOR (shorts)

    floatx4 acc[8][4];
#pragma unroll
    for (int i = 0; i < 8; ++i)
#pragma unroll
        for (int j = 0; j < 4; ++j) acc[i][j] = (floatx4)0.f;

    auto SPAIR = [&](int buf, int t, int pair) {
        unsigned short* as = &smem[buf * 32768];
        unsigned short* bs = as + 16384;
        const int k0 = t * 64;
        if (pair == 0) {
            gld_lds16(&BT[(size_t)(bn + 0 * 64 + sr) * 512 + k0 + scw], &bs[(0 * 64 + sr) * 64 + scl]);
            gld_lds16(&BT[(size_t)(bn + 1 * 64 + sr) * 512 + k0 + scw], &bs[(1 * 64 + sr) * 64 + scl]);
        } else if (pair == 1) {
            gld_lds16(&BT[(size_t)(bn + 2 * 64 + sr) * 512 + k0 + scw], &bs[(2 * 64 + sr) * 64 + scl]);
            gld_lds16(&BT[(size_t)(bn + 3 * 64 + sr) * 512 + k0 + scw], &bs[(3 * 64 + sr) * 64 + scl]);
        } else if (pair == 2) {
            gld_lds16(&A[(size_t)(bm + 0 * 64 + sr) * 512 + k0 + scw], &as[(0 * 64 + sr) * 64 + scl]);
            gld_lds16(&A[(size_t)(bm + 2 * 64 + sr) * 512 + k0 + scw], &as[(2 * 64 + sr) * 64 + scl]);
        } else {
            gld_lds16(&A[(size_t)(bm + 1 * 64 + sr) * 512 + k0 + scw], &as[(1 * 64 + sr) * 64 + scl]);
            gld_lds16(&A[(size_t)(bm + 3 * 64 + sr) * 512 + k0 + scw], &as[(3 * 64 + sr) * 64 + scl]);
        }
    };

    auto PHASE = [&](int buf, int qa, int qb, int stt, int pair) {
        const unsigned short* as = &smem[buf * 32768];
        const unsigned short* bs = as + 16384;
        bf16x8 af[4][2], bfr[2][2];
#pragma unroll
        for (int i4 = 0; i4 < 4; ++i4)
#pragma unroll
            for (int ks = 0; ks < 2; ++ks)
                af[i4][ks] = *(const bf16x8*)&as[(wm + (qa * 4 + i4) * 16 + lm) * 64 + ((ks * 32 + lq * 8) ^ rsw)];
#pragma unroll
        for (int j2 = 0; j2 < 2; ++j2)
#pragma unroll
            for (int ks = 0; ks < 2; ++ks)
                bfr[j2][ks] = *(const bf16x8*)&bs[(wn + (qb * 2 + j2) * 16 + lm) * 64 + ((ks * 32 + lq * 8) ^ rsw)];
        if (pair >= 0) SPAIR(buf ^ 1, stt, pair);
        __builtin_amdgcn_s_setprio(1);
#pragma unroll
        for (int i4 = 0; i4 < 4; ++i4)
#pragma unroll
            for (int j2 = 0; j2 < 2; ++j2)
#pragma unroll
                for (int ks = 0; ks < 2; ++ks)
                    acc[qa * 4 + i4][qb * 2 + j2] = __builtin_amdgcn_mfma_f32_16x16x32_bf16(
                        af[i4][ks], bfr[j2][ks], acc[qa * 4 + i4][qb * 2 + j2], 0, 0, 0);
        __builtin_amdgcn_s_setprio(0);
    };

    SPAIR(0, 0, 0); SPAIR(0, 0, 1); SPAIR(0, 0, 2); SPAIR(0, 0, 3);
    VMWAIT(2);
    __builtin_amdgcn_s_barrier();
    __builtin_amdgcn_sched_barrier(0);

#pragma unroll
    for (int t = 0; t < 8; ++t) {
        const int ct = t & 1;
        const bool st = (t < 7);
        PHASE(ct, 0, 0, t + 1, st ? 0 : -1);
        PHASE(ct, 0, 1, t + 1, st ? 1 : -1);
        if (st) { VMWAIT(4); } else { VMWAIT(0); }
        __builtin_amdgcn_s_barrier();
        __builtin_amdgcn_sched_barrier(0);
        PHASE(ct, 1, 0, t + 1, st ? 2 : -1);
        PHASE(ct, 1, 1, t + 1, st ? 3 : -1);
        if (st) {
            VMWAIT(2);
            __builtin_amdgcn_s_barrier();
            __builtin_amdgcn_sched_barrier(0);
        }
    }

    // ---- epilogue: write X (global) + tile (LDS), then carry scan from LDS ----
    __syncthreads();
#pragma unroll
    for (int i = 0; i < 8; ++i)
#pragma unroll
        for (int j = 0; j < 4; ++j) {
            int lcol = wn + j * 16 + lm;
#pragma unroll
            for (int r = 0; r < 4; ++r) {
                int lrow = wm + i * 16 + lq * 4 + r;
                unsigned short v = f2bf(acc[i][j][r]);
                smem[lrow * 256 + lcol] = v;
                X[(size_t)(bm + lrow) * 1024 + bn + lcol] = v;
            }
        }
    __syncthreads();
#pragma unroll
    for (int q = 0; q < 2; ++q) {
        const int s = tid + q * 512;
        const int chunk = s >> 7;                // 0..7 (32 rows each)
        const int ch = s & 127;
        const int n = (bn >> 1) + ch;
        const int gl = ch >> 6, cc = ch & 63;
        const int recol = gl * 128 + cc;
        const float rr = __expf(-__expf(nu[n]));
        const float lre = rr * __cosf(theta[n]);
        const float lim = rr * __sinf(theta[n]);
        const unsigned short* base = &smem[chunk * 32 * 256 + recol];
        float xre = 0.f, xim = 0.f;
#pragma unroll 8
        for (int t = 0; t < 32; ++t) {
            float ure = bf2f(base[t * 256]);
            float uim = bf2f(base[t * 256 + 64]);
            float a = lre * xre - lim * xim + ure;
            float b = lre * xim + lim * xre + uim;
            xre = a; xim = b;
        }
        const int bb = bm >> 11;
        const int cg = ((bm & 2047) >> 5) + chunk;
        size_t ci = ((size_t)bb * NCHUNK + cg) * NDIM + n;
        *(float2*)&carry[ci * 2] = make_float2(xre, xim);
    }
}

// -------- GEMM-out + in-block scan: Y = scan(X) @ CT^T + D*u ----------------
// 256x128 tile, 8 waves (4M x 2N). NO cross-block sync: all carries exist
// (kernel boundary). Per block: (1) chain prefixes for all 512 channels x 8
// chunks into LDS (identical op order to the old k_scan_apply chain);
// (2) per 128-col group g: scan 32-row chunks in VALU from pre-scan X and
// write post-scan bf16 directly into the swizzled LDS A-tile; (3) 2 K-tiles
// of MFMA per group against CT. RACE FIX vs round 10: the next-group CT
// prefetch is issued ONLY after the post-MFMA barrier (all waves done
// reading Bsm), and completes by the next group's post-scan __syncthreads
// (vmcnt(0) drain) — overlapping the latency-heavy scan phase.
__global__ __launch_bounds__(512) void k_gemm_out(
    const unsigned short* __restrict__ X,    // [16384][1024] bf16 (PRE-scan)
    const unsigned short* __restrict__ CT,   // [512][1024] bf16, n-major
    const float* __restrict__ nu, const float* __restrict__ theta,
    const float* __restrict__ carry,         // [b][c][n] float2 interleaved
    const float* __restrict__ D,
    const unsigned short* __restrict__ Ubf,  // [16384][512] bf16 (for D*u)
    float* __restrict__ Y)
{
    __shared__ unsigned short Asm[256 * 128];   // 64 KB post-scan A group tile (swz)
    __shared__ unsigned short Bsm[2][128 * 64]; // 2 x 16 KB CT tiles (swz)
    __shared__ float2 Pref[8][512];             // 32 KB exclusive prefixes
    __shared__ float2 Lam[512];                 // 4 KB lambda per channel

    const int tid = threadIdx.x;
    const int bm = blockIdx.x * 256;
    const int bn = blockIdx.y * 128;
    const int bb = bm >> 11;                 // batch
    const int cg0 = (bm & 2047) >> 5;        // first global chunk of block

    // CT staging: tile t covers cols [t*64,(t+1)*64). 2 ops x 512thr x 16B.
    // LDS physical slot p of row r holds logical k-slot p^(r&7).
    auto SB = [&](int buf, int t) {
        const int row = tid >> 3;            // 0..63
        const int slot = tid & 7;
        const int k0 = t * 64;
#pragma unroll
        for (int o = 0; o < 2; ++o) {
            int r = o * 64 + row;
            gld_lds16(&CT[(size_t)(bn + r) * 1024 + k0 + ((slot ^ (r & 7)) * 8)],
                      &Bsm[buf][r * 64 + slot * 8]);
        }
    };

    // prefetch group 0's two CT tiles under the prefix chain
    SB(0, 0);
    SB(1, 1);

    // ---- phase 1: lambda + exclusive prefixes for all 512 channels --------
    // Incremental chain == old k_scan_apply's loop (identical FP op order).
    {
        const int n = tid;
        const float ex = __expf(nu[n]);
        const float rr = __expf(-ex);
        const float lre = rr * __cosf(theta[n]);
        const float lim = rr * __sinf(theta[n]);
        Lam[n] = make_float2(lre, lim);
        const float rc = expf(-ex * (float)CHUNK);
        const float th = theta[n] * (float)CHUNK;
        const float A0 = rc * cosf(th), B0 = rc * sinf(th);
        float pre_re = 0.f, pre_im = 0.f;
        for (int cc = 0; cc < cg0; ++cc) {
            float2 cv = *(const float2*)&carry[(((size_t)bb * NCHUNK + cc) * NDIM + n) * 2];
            float a = A0 * pre_re - B0 * pre_im + cv.x;
            float b = A0 * pre_im + B0 * pre_re + cv.y;
            pre_re = a; pre_im = b;
        }
#pragma unroll
        for (int ck = 0; ck < 8; ++ck) {
            Pref[ck][n] = make_float2(pre_re, pre_im);
            float2 cv = *(const float2*)&carry[(((size_t)bb * NCHUNK + cg0 + ck) * NDIM + n) * 2];
            float a = A0 * pre_re - B0 * pre_im + cv.x;
            float b = A0 * pre_im + B0 * pre_re + cv.y;
            pre_re = a; pre_im = b;
        }
    }

    // ---- phases 2+3 per group: scan -> LDS A, then 2 K-tiles of MFMA ------
    const int wv = tid >> 6, l = tid & 63;
    const int wm = (wv & 3) * 64, wn = (wv >> 2) * 64;
    const int lm = l & 15, lq = l >> 4;
    const int sch = tid & 63;                // channel-in-group (scan role)
    const int schunk = tid >> 6;             // chunk 0..7 (scan role)

    floatx4 acc[4][4];
#pragma unroll
    for (int i = 0; i < 4; ++i)
#pragma unroll
        for (int j = 0; j < 4; ++j) acc[i][j] = (floatx4)0.f;

    __syncthreads();                         // Pref/Lam visible (CT 0,1 still in flight)

    for (int g = 0; g < 8; ++g) {
        // scan: thread (sch, schunk) scans 32 rows of channel g*64+sch.
        {
            const int n2 = g * 64 + sch;
            const float2 lam = Lam[n2];
            const float2 P = Pref[schunk][n2];
            float sre = P.x, sim = P.y;
            const unsigned short* xr = &X[(size_t)(bm + schunk * 32) * 1024 + g * 128 + sch];
            unsigned short* arow = &Asm[(schunk * 32) * 128 + (sch & 7)];
            const int sre_slot = sch >> 3;           // logical re slot 0..7
#pragma unroll 8
            for (int t = 0; t < 32; ++t) {
                float ure = bf2f(xr[(size_t)t * 1024]);
                float uim = bf2f(xr[(size_t)t * 1024 + 64]);
                float a = lam.x * sre - lam.y * sim + ure;
                float b = lam.x * sim + lam.y * sre + uim;
                sre = a; sim = b;
                const int sw = t & 7;                // row&7 (chunk*32 = 0 mod 8)
                arow[t * 128 + ((sre_slot ^ sw) * 8)] = f2bf(sre);
                arow[t * 128 + (((8 + sre_slot) ^ sw) * 8)] = f2bf(sim);
            }
        }
        __syncthreads();     // vmcnt(0) drain: this group's CT resident; A visible

        // MFMA: 2 K-tiles (ktl 0 = re cols, 1 = im cols of this group)
#pragma unroll
        for (int ktl = 0; ktl < 2; ++ktl) {
            bf16x8 af[4][2], bfr[4][2];
#pragma unroll
            for (int i = 0; i < 4; ++i)
#pragma unroll
                for (int ks = 0; ks < 2; ++ks) {
                    int row = wm + i * 16 + lm;
                    af[i][ks] = *(const bf16x8*)&Asm[row * 128 + (((ktl * 8 + ks * 4 + lq) ^ (lm & 7)) * 8)];
                }
#pragma unroll
            for (int j = 0; j < 4; ++j)
#pragma unroll
                for (int ks = 0; ks < 2; ++ks) {
                    int row = wn + j * 16 + lm;
                    bfr[j][ks] = *(const bf16x8*)&Bsm[ktl][row * 64 + (((ks * 4 + lq) ^ (lm & 7)) * 8)];
                }
            __builtin_amdgcn_s_setprio(1);
#pragma unroll
            for (int i = 0; i < 4; ++i)
#pragma unroll
                for (int j = 0; j < 4; ++j)
#pragma unroll
                    for (int ks = 0; ks < 2; ++ks)
                        acc[i][j] = __builtin_amdgcn_mfma_f32_16x16x32_bf16(
                            af[i][ks], bfr[j][ks], acc[i][j], 0, 0, 0);
            __builtin_amdgcn_s_setprio(0);
        }
        __syncthreads();     // ALL waves done reading Asm + Bsm
        // RACE FIX: only now overwrite Bsm with next group's CT. These loads
        // overlap the next scan phase; resident by its post-scan barrier.
        if (g < 7) { SB(0, 2 * g + 2); SB(1, 2 * g + 3); }
    }

    // ---- epilogue: Y = acc + D*u ----
#pragma unroll
    for (int i = 0; i < 4; ++i)
#pragma unroll
        for (int j = 0; j < 4; ++j) {
            int col = bn + wn + j * 16 + lm;
            float dv = D[col];
#pragma unroll
            for (int r = 0; r < 4; ++r) {
                int row = bm + wm + i * 16 + lq * 4 + r;
                size_t off = (size_t)row * NDIM + col;
                Y[off] = acc[i][j][r] + dv * bf2f(Ubf[off]);
            }
        }
}

extern "C" void kernel_launch(void* const* d_in, const int* in_sizes, int n_in,
                              void* d_out, int out_size, void* d_ws, size_t ws_size,
                              hipStream_t stream)
{
    const float* u     = (const float*)d_in[0];
    const float* C_re  = (const float*)d_in[1];
    const float* C_im  = (const float*)d_in[2];
    const float* B_re  = (const float*)d_in[3];
    const float* B_im  = (const float*)d_in[4];
    const float* D     = (const float*)d_in[5];
    const float* nu    = (const float*)d_in[6];
    const float* theta = (const float*)d_in[7];
    const float* gamma = (const float*)d_in[8];
    float* y = (float*)d_out;

    // Workspace (52 MB): X 32MB | ubf 16MB | BT 1MB | CT 1MB | carry 2MB
    unsigned short* X   = (unsigned short*)d_ws;
    unsigned short* ubf = X + (size_t)M_ROWS * 1024;
    unsigned short* BT  = ubf + (size_t)M_ROWS * 512;
    unsigned short* CT  = BT + (size_t)1024 * 512;
    float* carry = (float*)(CT + (size_t)512 * 1024);

    k_prep<<<4096 + 1024, 256, 0, stream>>>(u, B_re, B_im, C_re, C_im, gamma, ubf, BT, CT);
    k_gemm_in<<<dim3(M_ROWS / 256, 4), 512, 0, stream>>>(ubf, BT, nu, theta, X, carry);
    k_gemm_out<<<dim3(M_ROWS / 256, 4), 512, 0, stream>>>(X, CT, nu, theta, carry, D, ubf, y);
}

// Round 12
// 164.079 us; speedup vs baseline: 1.0793x; 1.0793x over previous
//
#include <hip/hip_runtime.h>
#include <hip/hip_bf16.h>
#include <math.h>
#include <stdint.h>

// Problem constants (reference: BATCH=8, T=2048, N=512)
#define BATCH 8
#define T_LEN 2048
#define NDIM 512
#define M_ROWS (BATCH * T_LEN)   // 16384
#define CHUNK 32                 // scan chunk length
#define NCHUNK (T_LEN / CHUNK)   // 64

// X column layout (group-paired so one GEMM col-tile holds re+im of the
// same channels): col g*128 + j  (j<64)  = re of channel n = g*64+j
//                 col g*128 + 64 + j     = im of channel n = g*64+j

typedef __attribute__((ext_vector_type(8))) short bf16x8;
typedef __attribute__((ext_vector_type(4))) float floatx4;

// counted vmcnt wait (T4): wave waits until only n of its VMEM ops remain
// in flight; the following s_barrier makes completion collective.
#define VMWAIT(n) asm volatile("s_waitcnt vmcnt(" #n ")" ::: "memory")

__device__ __forceinline__ unsigned short f2bf(float f) {
    union { float f; unsigned u; } v; v.f = f;
    unsigned r = v.u + 0x7fff + ((v.u >> 16) & 1);   // RTNE
    return (unsigned short)(r >> 16);
}
__device__ __forceinline__ float bf2f(unsigned short h) {
    union { unsigned u; float f; } v; v.u = ((unsigned)h) << 16;
    return v.f;
}
__device__ __forceinline__ float bf2f_lo(unsigned u) {
    union { unsigned u; float f; } v; v.u = u << 16; return v.f;
}
__device__ __forceinline__ float bf2f_hi(unsigned u) {
    union { unsigned u; float f; } v; v.u = u & 0xffff0000u; return v.f;
}

// async global->LDS, 16 bytes per lane; LDS dest = wave-uniform base + lane*16.
__device__ __forceinline__ void gld_lds16(const unsigned short* g, unsigned short* l) {
    __builtin_amdgcn_global_load_lds(
        (const __attribute__((address_space(1))) unsigned int*)(uintptr_t)g,
        (__attribute__((address_space(3))) unsigned int*)(uintptr_t)l,
        16, 0, 0);
}

// ---------------- prep (merged): u->bf16  +  transpose/convert B,C ----------
__global__ __launch_bounds__(256) void k_prep(
    const float* __restrict__ u,
    const float* __restrict__ Bre, const float* __restrict__ Bim,
    const float* __restrict__ Cre, const float* __restrict__ Cim,
    const float* __restrict__ gamma,
    unsigned short* __restrict__ ubf,
    unsigned short* __restrict__ BT, unsigned short* __restrict__ CT)
{
    __shared__ unsigned short tile[32][33];
    const int blk = blockIdx.x;
    if (blk < 4096) {
        size_t i = ((size_t)blk * 256 + threadIdx.x) * 8;
        float4 a = *(const float4*)&u[i];
        float4 b = *(const float4*)&u[i + 4];
        ushort4 p0, p1;
        p0.x = f2bf(a.x); p0.y = f2bf(a.y); p0.z = f2bf(a.z); p0.w = f2bf(a.w);
        p1.x = f2bf(b.x); p1.y = f2bf(b.y); p1.z = f2bf(b.z); p1.w = f2bf(b.w);
        *(ushort4*)&ubf[i] = p0;
        *(ushort4*)&ubf[i + 4] = p1;
        return;
    }
    const int p = blk - 4096;
    const int z = p >> 8;                    // 0..3 (Bre,Bim,Cre,Cim)
    const int rem = p & 255;
    const int n0 = (rem & 15) * 32, k0 = (rem >> 4) * 32;
    const float* __restrict__ src = (z == 0) ? Bre : (z == 1) ? Bim : (z == 2) ? Cre : Cim;
    const int tx = threadIdx.x & 31, ty = threadIdx.x >> 5;   // ty 0..7

#pragma unroll
    for (int j = 0; j < 4; ++j) {
        int k = k0 + ty + j * 8;
        float s = (z < 2) ? gamma[k] : (z == 3 ? -1.f : 1.f);
        tile[ty + j * 8][tx] = f2bf(s * src[(size_t)k * NDIM + n0 + tx]);
    }
    __syncthreads();
#pragma unroll
    for (int j = 0; j < 4; ++j) {
        int n = n0 + ty + j * 8;
        unsigned short v = tile[tx][ty + j * 8];
        if (z == 0) {
            int row = ((n >> 6) << 7) + (n & 63);            // re-col of channel n
            BT[(size_t)row * 512 + k0 + tx] = v;
        } else if (z == 1) {
            int row = ((n >> 6) << 7) + 64 + (n & 63);       // im-col of channel n
            BT[(size_t)row * 512 + k0 + tx] = v;
        } else if (z == 2) {
            int k = k0 + tx;
            int col = ((k >> 6) << 7) + (k & 63);            // X re-col of channel k
            CT[(size_t)n * 1024 + col] = v;
        } else {
            int k = k0 + tx;
            int col = ((k >> 6) << 7) + 64 + (k & 63);       // X im-col of channel k
            CT[(size_t)n * 1024 + col] = v;
        }
    }
}

// ---------------- GEMM-in: X[16384][1024] = ubf[16384][512] @ BT^T ----------
// 256x256 tile, BK=64, 8 waves (2M x 4N), 2 LDS buffers, 4-phase-per-K-tile
// interleave (T3) with counted vmcnt (T4) + setprio (T5) + T2 swizzle.
// Fused scan pass A from the LDS-resident 256x256 output tile.
__global__ __launch_bounds__(512) void k_gemm_in(
    const unsigned short* __restrict__ A,    // [16384][512] bf16
    const unsigned short* __restrict__ BT,   // [1024][512] bf16, X-col-major
    const float* __restrict__ nu, const float* __restrict__ theta,
    unsigned short* __restrict__ X,          // [16384][1024] bf16 out (pre-scan)
    float* __restrict__ carry)               // [b][c][n] float2 interleaved
{
    // 128 KB: 2 buffers x (As 256x64 | Bs 256x64) shorts.
    // Epilogue reuses all 65536 shorts as the [256][256] bf16 output tile.
    __shared__ unsigned short smem[65536];

    const int tid = threadIdx.x;
    const int w = tid >> 6, l = tid & 63;
    const int bm = blockIdx.x * 256;
    const int bn = blockIdx.y * 256;         // 256 X-cols = 128 channels
    const int wm = (w & 1) * 128, wn = (w >> 1) * 64;
    const int lm = l & 15, lq = l >> 4;
    // staging geometry: 512 thr x 16B = 8 KB = 64 rows of 128B per gld op
    const int sr = tid >> 3;                         // 0..63
    const int scw = ((tid & 7) ^ (sr & 7)) * 8;      // swizzled global col (shorts)
    const int scl = (tid & 7) * 8;                   // linear LDS col (shorts)
    const int rsw = (lm & 7) << 3;                   // read-side XOR (shorts)

    floatx4 acc[8][4];
#pragma unroll
    for (int i = 0; i < 8; ++i)
#pragma unroll
        for (int j = 0; j < 4; ++j) acc[i][j] = (floatx4)0.f;

    // stage one pair of 8KB ops for tile t into buffer buf.
    auto SPAIR = [&](int buf, int t, int pair) {
        unsigned short* as = &smem[buf * 32768];
        unsigned short* bs = as + 16384;
        const int k0 = t * 64;
        if (pair == 0) {
            gld_lds16(&BT[(size_t)(bn + 0 * 64 + sr) * 512 + k0 + scw], &bs[(0 * 64 + sr) * 64 + scl]);
            gld_lds16(&BT[(size_t)(bn + 1 * 64 + sr) * 512 + k0 + scw], &bs[(1 * 64 + sr) * 64 + scl]);
        } else if (pair == 1) {
            gld_lds16(&BT[(size_t)(bn + 2 * 64 + sr) * 512 + k0 + scw], &bs[(2 * 64 + sr) * 64 + scl]);
            gld_lds16(&BT[(size_t)(bn + 3 * 64 + sr) * 512 + k0 + scw], &bs[(3 * 64 + sr) * 64 + scl]);
        } else if (pair == 2) {
            gld_lds16(&A[(size_t)(bm + 0 * 64 + sr) * 512 + k0 + scw], &as[(0 * 64 + sr) * 64 + scl]);
            gld_lds16(&A[(size_t)(bm + 2 * 64 + sr) * 512 + k0 + scw], &as[(2 * 64 + sr) * 64 + scl]);
        } else {
            gld_lds16(&A[(size_t)(bm + 1 * 64 + sr) * 512 + k0 + scw], &as[(1 * 64 + sr) * 64 + scl]);
            gld_lds16(&A[(size_t)(bm + 3 * 64 + sr) * 512 + k0 + scw], &as[(3 * 64 + sr) * 64 + scl]);
        }
    };

    // one phase: quadrant (qa,qb) of tile in buf: 12 ds_read + optional 2 gld
    // for tile stt into buf^1 + 16 MFMA under setprio.
    auto PHASE = [&](int buf, int qa, int qb, int stt, int pair) {
        const unsigned short* as = &smem[buf * 32768];
        const unsigned short* bs = as + 16384;
        bf16x8 af[4][2], bfr[2][2];
#pragma unroll
        for (int i4 = 0; i4 < 4; ++i4)
#pragma unroll
            for (int ks = 0; ks < 2; ++ks)
                af[i4][ks] = *(const bf16x8*)&as[(wm + (qa * 4 + i4) * 16 + lm) * 64 + ((ks * 32 + lq * 8) ^ rsw)];
#pragma unroll
        for (int j2 = 0; j2 < 2; ++j2)
#pragma unroll
            for (int ks = 0; ks < 2; ++ks)
                bfr[j2][ks] = *(const bf16x8*)&bs[(wn + (qb * 2 + j2) * 16 + lm) * 64 + ((ks * 32 + lq * 8) ^ rsw)];
        if (pair >= 0) SPAIR(buf ^ 1, stt, pair);
        __builtin_amdgcn_s_setprio(1);
#pragma unroll
        for (int i4 = 0; i4 < 4; ++i4)
#pragma unroll
            for (int j2 = 0; j2 < 2; ++j2)
#pragma unroll
                for (int ks = 0; ks < 2; ++ks)
                    acc[qa * 4 + i4][qb * 2 + j2] = __builtin_amdgcn_mfma_f32_16x16x32_bf16(
                        af[i4][ks], bfr[j2][ks], acc[qa * 4 + i4][qb * 2 + j2], 0, 0, 0);
        __builtin_amdgcn_s_setprio(0);
    };

    // prologue: stage all of tile 0; need ops0-5 before phase 0.
    SPAIR(0, 0, 0); SPAIR(0, 0, 1); SPAIR(0, 0, 2); SPAIR(0, 0, 3);
    VMWAIT(2);
    __builtin_amdgcn_s_barrier();
    __builtin_amdgcn_sched_barrier(0);

#pragma unroll
    for (int t = 0; t < 8; ++t) {
        const int ct = t & 1;
        const bool st = (t < 7);
        PHASE(ct, 0, 0, t + 1, st ? 0 : -1);
        PHASE(ct, 0, 1, t + 1, st ? 1 : -1);
        if (st) { VMWAIT(4); } else { VMWAIT(0); }
        __builtin_amdgcn_s_barrier();
        __builtin_amdgcn_sched_barrier(0);
        PHASE(ct, 1, 0, t + 1, st ? 2 : -1);
        PHASE(ct, 1, 1, t + 1, st ? 3 : -1);
        if (st) {
            VMWAIT(2);
            __builtin_amdgcn_s_barrier();
            __builtin_amdgcn_sched_barrier(0);
        }
    }

    // ---- epilogue: write X (global) + tile (LDS), then carry scan from LDS ----
    __syncthreads();                             // all compute done; smem reusable
#pragma unroll
    for (int i = 0; i < 8; ++i)
#pragma unroll
        for (int j = 0; j < 4; ++j) {
            int lcol = wn + j * 16 + lm;                 // local col 0..255
#pragma unroll
            for (int r = 0; r < 4; ++r) {
                int lrow = wm + i * 16 + lq * 4 + r;     // local row 0..255
                unsigned short v = f2bf(acc[i][j][r]);
                smem[lrow * 256 + lcol] = v;
                X[(size_t)(bm + lrow) * 1024 + bn + lcol] = v;
            }
        }
    __syncthreads();
    // 8 chunks x 128 channels = 1024 scans; 512 threads -> 2 scans each.
#pragma unroll
    for (int q = 0; q < 2; ++q) {
        const int s = tid + q * 512;
        const int chunk = s >> 7;                // 0..7 (32 rows each)
        const int ch = s & 127;                  // channel within block
        const int n = (bn >> 1) + ch;            // global channel
        const int gl = ch >> 6, cc = ch & 63;
        const int recol = gl * 128 + cc;
        const float rr = __expf(-__expf(nu[n]));
        const float lre = rr * __cosf(theta[n]);
        const float lim = rr * __sinf(theta[n]);
        // same row across lanes, distinct cols -> 2-way max, free.
        const unsigned short* base = &smem[chunk * 32 * 256 + recol];
        float xre = 0.f, xim = 0.f;
#pragma unroll 8
        for (int t = 0; t < 32; ++t) {
            float ure = bf2f(base[t * 256]);
            float uim = bf2f(base[t * 256 + 64]);
            float a = lre * xre - lim * xim + ure;
            float b = lre * xim + lim * xre + uim;
            xre = a; xim = b;
        }
        const int bb = bm >> 11;                         // batch (2048 rows each)
        const int cg = ((bm & 2047) >> 5) + chunk;       // global chunk id 0..63
        size_t ci = ((size_t)bb * NCHUNK + cg) * NDIM + n;
        *(float2*)&carry[ci * 2] = make_float2(xre, xim);
    }
}

// ------- Scan pass B+C fused: chain own prefix from carries, then apply -----
__global__ __launch_bounds__(256) void k_scan_apply(
    unsigned short* __restrict__ X,
    const float* __restrict__ nu, const float* __restrict__ theta,
    const float* __restrict__ carry)
{
    const int t2 = threadIdx.x;                 // handles n = 2*t2, 2*t2+1
    const int n0 = 2 * t2;
    const int b = blockIdx.x >> 6, c = blockIdx.x & 63;
    const float ex0 = __expf(nu[n0]), ex1 = __expf(nu[n0 + 1]);
    const float r0 = __expf(-ex0), r1 = __expf(-ex1);
    const float lre0 = r0 * __cosf(theta[n0]),     lim0 = r0 * __sinf(theta[n0]);
    const float lre1 = r1 * __cosf(theta[n0 + 1]), lim1 = r1 * __sinf(theta[n0 + 1]);
    const float rc0 = expf(-ex0 * (float)CHUNK), rc1 = expf(-ex1 * (float)CHUNK);
    const float th0 = theta[n0] * (float)CHUNK,  th1 = theta[n0 + 1] * (float)CHUNK;
    const float A0 = rc0 * cosf(th0), B0 = rc0 * sinf(th0);
    const float A1 = rc1 * cosf(th1), B1 = rc1 * sinf(th1);

    float xre0 = 0.f, xim0 = 0.f, xre1 = 0.f, xim1 = 0.f;
    for (int cc = 0; cc < c; ++cc) {            // chain: exclusive prefix
        size_t idx = ((size_t)b * NCHUNK + cc) * NDIM + n0;
        float4 cv = *(const float4*)&carry[idx * 2];
        float a0 = A0 * xre0 - B0 * xim0 + cv.x;
        float b0 = A0 * xim0 + B0 * xre0 + cv.y;
        float a1 = A1 * xre1 - B1 * xim1 + cv.z;
        float b1 = A1 * xim1 + B1 * xre1 + cv.w;
        xre0 = a0; xim0 = b0; xre1 = a1; xim1 = b1;
    }

    const int recol = ((n0 >> 6) << 7) + (n0 & 63);   // paired layout
    size_t m = (size_t)b * T_LEN + (size_t)c * CHUNK;
#pragma unroll 8
    for (int t = 0; t < CHUNK; ++t, ++m) {
        unsigned re = *(const unsigned*)&X[m * 1024 + recol];
        unsigned im = *(const unsigned*)&X[m * 1024 + recol + 64];
        float u0 = bf2f_lo(re), u1 = bf2f_hi(re);
        float v0 = bf2f_lo(im), v1 = bf2f_hi(im);
        float a0 = lre0 * xre0 - lim0 * xim0 + u0;
        float b0 = lre0 * xim0 + lim0 * xre0 + v0;
        float a1 = lre1 * xre1 - lim1 * xim1 + u1;
        float b1 = lre1 * xim1 + lim1 * xre1 + v1;
        xre0 = a0; xim0 = b0; xre1 = a1; xim1 = b1;
        unsigned pr = (unsigned)f2bf(xre0) | ((unsigned)f2bf(xre1) << 16);
        unsigned pim = (unsigned)f2bf(xim0) | ((unsigned)f2bf(xim1) << 16);
        *(unsigned*)&X[m * 1024 + recol] = pr;
        *(unsigned*)&X[m * 1024 + recol + 64] = pim;
    }
}

// ---------------- GEMM-out: Y = X[16384][1024] @ CT^T + D*u -----------------
// 256x128 tile, BK=64, 8 waves (4M x 2N), 3 LDS buffers (144 KB), 2 phases
// per K-tile, tile t+2 staged during tile t -> boundary vmcnt(6) with a full
// K-tile of slack. T2 swizzle + setprio.
__global__ __launch_bounds__(512) void k_gemm_out(
    const unsigned short* __restrict__ Xbf,  // [16384][1024] bf16
    const unsigned short* __restrict__ CT,   // [512][1024] bf16, n-major
    const float* __restrict__ D,
    const unsigned short* __restrict__ Ubf,  // [16384][512] bf16 (for D*u)
    float* __restrict__ Y)
{
    // 144 KB: 3 buffers x (As 256x64 = 16384 | Bs 128x64 = 8192) shorts.
    __shared__ unsigned short smem[73728];

    const int tid = threadIdx.x;
    const int w = tid >> 6, l = tid & 63;
    const int bm = blockIdx.x * 256;
    const int bn = blockIdx.y * 128;
    const int wm = (w & 3) * 64, wn = (w >> 2) * 64;
    const int lm = l & 15, lq = l >> 4;
    const int sr = tid >> 3;                         // 0..63
    const int scw = ((tid & 7) ^ (sr & 7)) * 8;      // swizzled global col (shorts)
    const int scl = (tid & 7) * 8;                   // linear LDS col (shorts)
    const int rsw = (lm & 7) << 3;                   // read-side XOR (shorts)

    floatx4 acc[4][4];
#pragma unroll
    for (int i = 0; i < 4; ++i)
#pragma unroll
        for (int j = 0; j < 4; ++j) acc[i][j] = (floatx4)0.f;

    // stage half of tile t's 6 ops into buffer buf (half 0: A0,A1,B0; 1: A2,A3,B1)
    auto SHALF = [&](int buf, int t, int half) {
        unsigned short* as = &smem[buf * 24576];
        unsigned short* bs = as + 16384;
        const int k0 = t * 64;
        if (half == 0) {
            gld_lds16(&Xbf[(size_t)(bm + 0 * 64 + sr) * 1024 + k0 + scw], &as[(0 * 64 + sr) * 64 + scl]);
            gld_lds16(&Xbf[(size_t)(bm + 1 * 64 + sr) * 1024 + k0 + scw], &as[(1 * 64 + sr) * 64 + scl]);
            gld_lds16(&CT[(size_t)(bn + 0 * 64 + sr) * 1024 + k0 + scw],  &bs[(0 * 64 + sr) * 64 + scl]);
        } else {
            gld_lds16(&Xbf[(size_t)(bm + 2 * 64 + sr) * 1024 + k0 + scw], &as[(2 * 64 + sr) * 64 + scl]);
            gld_lds16(&Xbf[(size_t)(bm + 3 * 64 + sr) * 1024 + k0 + scw], &as[(3 * 64 + sr) * 64 + scl]);
            gld_lds16(&CT[(size_t)(bn + 1 * 64 + sr) * 1024 + k0 + scw],  &bs[(1 * 64 + sr) * 64 + scl]);
        }
    };

    // phase p (j-half) of tile in buf: 12 ds_read + optional 3 gld + 16 MFMA.
    auto PHASE = [&](int buf, int p, int sbuf, int stt, int half) {
        const unsigned short* as = &smem[buf * 24576];
        const unsigned short* bs = as + 16384;
        bf16x8 af[4][2], bfr[2][2];
#pragma unroll
        for (int i = 0; i < 4; ++i)
#pragma unroll
            for (int ks = 0; ks < 2; ++ks)
                af[i][ks] = *(const bf16x8*)&as[(wm + i * 16 + lm) * 64 + ((ks * 32 + lq * 8) ^ rsw)];
#pragma unroll
        for (int j2 = 0; j2 < 2; ++j2)
#pragma unroll
            for (int ks = 0; ks < 2; ++ks)
                bfr[j2][ks] = *(const bf16x8*)&bs[(wn + (p * 2 + j2) * 16 + lm) * 64 + ((ks * 32 + lq * 8) ^ rsw)];
        if (half >= 0) SHALF(sbuf, stt, half);
        __builtin_amdgcn_s_setprio(1);
#pragma unroll
        for (int i = 0; i < 4; ++i)
#pragma unroll
            for (int j2 = 0; j2 < 2; ++j2)
#pragma unroll
                for (int ks = 0; ks < 2; ++ks)
                    acc[i][p * 2 + j2] = __builtin_amdgcn_mfma_f32_16x16x32_bf16(
                        af[i][ks], bfr[j2][ks], acc[i][p * 2 + j2], 0, 0, 0);
        __builtin_amdgcn_s_setprio(0);
    };

    // prologue: stage tiles 0 and 1; wait tile 0 (6 ops of tile 1 in flight).
    SHALF(0, 0, 0); SHALF(0, 0, 1);
    SHALF(1, 1, 0); SHALF(1, 1, 1);
    VMWAIT(6);
    __builtin_amdgcn_s_barrier();
    __builtin_amdgcn_sched_barrier(0);

    // NT = 16 K-tiles of 64. Compute tile t from buf t%3; stage t+2 into (t+2)%3.
#pragma unroll
    for (int t = 0; t < 16; ++t) {
        const int ct = t % 3;
        const int sb = (t + 2) % 3;
        const bool st = (t < 14);
        PHASE(ct, 0, sb, t + 2, st ? 0 : -1);
        PHASE(ct, 1, sb, t + 2, st ? 1 : -1);
        if (t < 15) {
            if (st) { VMWAIT(6); } else { VMWAIT(0); }
            __builtin_amdgcn_s_barrier();
            __builtin_amdgcn_sched_barrier(0);
        }
    }

#pragma unroll
    for (int i = 0; i < 4; ++i)
#pragma unroll
        for (int j = 0; j < 4; ++j) {
            int col = bn + wn + j * 16 + lm;
            float dv = D[col];
#pragma unroll
            for (int r = 0; r < 4; ++r) {
                int row = bm + wm + i * 16 + lq * 4 + r;
                size_t off = (size_t)row * NDIM + col;
                Y[off] = acc[i][j][r] + dv * bf2f(Ubf[off]);
            }
        }
}

extern "C" void kernel_launch(void* const* d_in, const int* in_sizes, int n_in,
                              void* d_out, int out_size, void* d_ws, size_t ws_size,
                              hipStream_t stream)
{
    const float* u     = (const float*)d_in[0];
    const float* C_re  = (const float*)d_in[1];
    const float* C_im  = (const float*)d_in[2];
    const float* B_re  = (const float*)d_in[3];
    const float* B_im  = (const float*)d_in[4];
    const float* D     = (const float*)d_in[5];
    const float* nu    = (const float*)d_in[6];
    const float* theta = (const float*)d_in[7];
    const float* gamma = (const float*)d_in[8];
    float* y = (float*)d_out;

    // Workspace (52 MB): X 32MB | ubf 16MB | BT 1MB | CT 1MB | carry 2MB
    unsigned short* X   = (unsigned short*)d_ws;
    unsigned short* ubf = X + (size_t)M_ROWS * 1024;
    unsigned short* BT  = ubf + (size_t)M_ROWS * 512;
    unsigned short* CT  = BT + (size_t)1024 * 512;
    float* carry = (float*)(CT + (size_t)512 * 1024);

    k_prep<<<4096 + 1024, 256, 0, stream>>>(u, B_re, B_im, C_re, C_im, gamma, ubf, BT, CT);
    k_gemm_in<<<dim3(M_ROWS / 256, 4), 512, 0, stream>>>(ubf, BT, nu, theta, X, carry);
    k_scan_apply<<<BATCH * NCHUNK, 256, 0, stream>>>(X, nu, theta, carry);
    k_gemm_out<<<dim3(M_ROWS / 256, 4), 512, 0, stream>>>(X, CT, D, ubf, y);
}